// Round 11
// baseline (164.630 us; speedup 1.0000x reference)
//
#include <hip/hip_runtime.h>

#define NPTS  65536
#define NBC   76
#define NREP  8
#define KEYN  4864   // 76*64

typedef _Float16 f16;
typedef __fp16   h16x2 __attribute__((ext_vector_type(2)));   // cvt_pkrtz native type
typedef _Float16 f16x8 __attribute__((ext_vector_type(8)));
typedef float    f32x4 __attribute__((ext_vector_type(4)));

__device__ __forceinline__ float lrelu(float v) { return fmaxf(v, 0.01f * v); }

__device__ __forceinline__ unsigned pkrtz(float lo, float hi) {
  h16x2 p = __builtin_amdgcn_cvt_pkrtz(lo, hi);
  return __builtin_bit_cast(unsigned, p);
}
// packed f16 bits -> packed order-preserving u16 keys (larger key = larger float).
// Key 0 requires a NaN bit pattern => valid keys are in [1, 0xFFFF].
__device__ __forceinline__ unsigned pkey(unsigned u) {
  unsigned t = (u >> 15) & 0x00010001u;
  return u ^ (0x80008000u | (t * 0x7FFFu));
}
__device__ __forceinline__ unsigned pkmax(unsigned a, unsigned b) {
  unsigned d;
  asm("v_pk_max_u16 %0, %1, %2" : "=v"(d) : "v"(a), "v"(b));
  return d;
}
__device__ __forceinline__ unsigned sext1(unsigned x, int b) {
  return (unsigned)(((int)(x << (31 - b))) >> 31);
}
// 8 contiguous f32 -> f16x8 fragment (register-resident MFMA A-operand)
__device__ __forceinline__ f16x8 ldcvt8(const float* p) {
  float4 a = *(const float4*)p, b = *(const float4*)(p + 4);
  uint4 u = make_uint4(pkrtz(a.x, a.y), pkrtz(a.z, a.w),
                       pkrtz(b.x, b.y), pkrtz(b.z, b.w));
  return __builtin_bit_cast(f16x8, u);
}

// MFMA layer with register A-frags: acc = bias; 2 k-steps x 2 pt-tiles
__device__ __forceinline__ void mfma_layer_r(
    const f16x8* wr, const f16* __restrict__ B, const float* __restrict__ bias,
    int chq, int q, int pt0, int pt1, f32x4& acc0, f32x4& acc1)
{
  float4 bv = *(const float4*)(bias + chq);
  acc0 = (f32x4){bv.x, bv.y, bv.z, bv.w};
  acc1 = acc0;
  #pragma unroll
  for (int s = 0; s < 2; ++s) {
    int k0 = s * 32;
    f16x8 b0 = *(const f16x8*)&B[pt0 * 72 + k0 + q * 8];
    f16x8 b1 = *(const f16x8*)&B[pt1 * 72 + k0 + q * 8];
    acc0 = __builtin_amdgcn_mfma_f32_16x16x32_f16(wr[s], b0, acc0, 0, 0, 0);
    acc1 = __builtin_amdgcn_mfma_f32_16x16x32_f16(wr[s], b1, acc1, 0, 0, 0);
  }
}

// ------------- kAB: MLP (f16 MFMA) + masked max, fused, T=1, 1024 blocks -------
// keys: NO pre-zeroing. Signed atomicMax: poison 0xAAAAAAAA is negative, valid
// keys are [1,0xFFFF] (positive) -> untouched slots lose every signed max; k2
// decodes (unsigned)(m-1) < 0xFFFF as "touched". Works for 0xAA or 0 init.
__global__ __launch_bounds__(512, 8) void kAB(
    const int* __restrict__ x, const float* __restrict__ grid,
    const float* __restrict__ w1, const float* __restrict__ b1,
    const float* __restrict__ w2, const float* __restrict__ b2,
    const float* __restrict__ w3, const float* __restrict__ b3,
    int* __restrict__ keys)
{
  // zA [64pt][72k] f16 (9216 B), zB same; zk [32][68] u32 (8704 B) aliases zA.
  // ~19 KB total -> LDS allows 8 blocks/CU; grid 1024 gives 4 -> 8 waves/SIMD.
  __shared__ __align__(16) unsigned char smem[18432];
  __shared__ unsigned long long mbits[NBC];
  f16* zA = (f16*)(smem);
  f16* zB = (f16*)(smem + 9216);
  unsigned* zk = (unsigned*)(smem);           // alias zA (dead after layer2)

  const int t = threadIdx.x, lane = t & 63, wv = t >> 6;
  const int n0 = blockIdx.x * 64;

  // ---- x loads first: ~900cyc HBM latency hides under weight cvt + layer1
  int xa[10];
  #pragma unroll
  for (int i = 0; i < 10; ++i) {
    int bc = wv + 8 * i;
    if (bc < NBC) xa[i] = x[(bc << 16) + n0 + lane];
  }

  float g0 = grid[n0 + lane], g1 = grid[NPTS + n0 + lane];

  const int chb = (wv & 3) * 16, pth = (wv >> 2) * 32;
  const int c15 = lane & 15, q = lane >> 4;
  const int chq = chb + q * 4;
  const int pt0 = pth + c15, pt1 = pth + 16 + c15;
  const int r0 = chq >> 1;

  // weight A-fragments straight to registers
  f16x8 wr2[2], wr3[2];
  {
    const int row = (chb + c15) * 64 + q * 8;
    wr2[0] = ldcvt8(w2 + row);  wr2[1] = ldcvt8(w2 + row + 32);
    wr3[0] = ldcvt8(w3 + row);  wr3[1] = ldcvt8(w3 + row + 32);
  }

  // layer 1: wave wv -> channels wv*8..+7, pt = lane
  {
    unsigned uo[4];
    #pragma unroll
    for (int p = 0; p < 4; ++p) {
      int j = wv * 8 + p * 2;
      float z0 = lrelu(w1[2 * j] * g0 + w1[2 * j + 1] * g1 + b1[j]);
      float z1 = lrelu(w1[2 * j + 2] * g0 + w1[2 * j + 3] * g1 + b1[j + 1]);
      uo[p] = pkrtz(z0, z1);
    }
    *(uint4*)&zA[lane * 72 + wv * 8] = make_uint4(uo[0], uo[1], uo[2], uo[3]);
  }

  // ballots (xa long since arrived)
  #pragma unroll
  for (int i = 0; i < 10; ++i) {
    int bc = wv + 8 * i;
    if (bc < NBC) {
      unsigned long long m = __ballot(xa[i] == 1);
      if (lane == 0) mbits[bc] = m;
    }
  }
  __syncthreads();                      // barrier 1: zA ready

  f32x4 a0, a1;
  mfma_layer_r(wr2, zA, b2, chq, q, pt0, pt1, a0, a1);
  *(uint2*)&zB[pt0 * 72 + chq] =
      make_uint2(pkrtz(lrelu(a0[0]), lrelu(a0[1])), pkrtz(lrelu(a0[2]), lrelu(a0[3])));
  *(uint2*)&zB[pt1 * 72 + chq] =
      make_uint2(pkrtz(lrelu(a1[0]), lrelu(a1[1])), pkrtz(lrelu(a1[2]), lrelu(a1[3])));
  __syncthreads();                      // barrier 2: zB ready, zA dead

  mfma_layer_r(wr3, zB, b3, chq, q, pt0, pt1, a0, a1);
  zk[r0 * 68 + pt0]       = pkey(pkrtz(lrelu(a0[0]), lrelu(a0[1])));
  zk[(r0 + 1) * 68 + pt0] = pkey(pkrtz(lrelu(a0[2]), lrelu(a0[3])));
  zk[r0 * 68 + pt1]       = pkey(pkrtz(lrelu(a1[0]), lrelu(a1[1])));
  zk[(r0 + 1) * 68 + pt1] = pkey(pkrtz(lrelu(a1[2]), lrelu(a1[3])));
  __syncthreads();                      // barrier 3: zk + masks ready

  // ---- phase B: thread -> row rw (ch pair) x 5 bc
  const int rw = t & 31, bg = t >> 5;
  const int bc0 = bg * 5;

  unsigned uacc[5] = {0u, 0u, 0u, 0u, 0u};
  unsigned mlo[5], mhi[5];
  #pragma unroll
  for (int ii = 0; ii < 5; ++ii) {
    int bc = bc0 + ii;
    unsigned long long m = (bc < NBC) ? mbits[bc] : 0ull;
    mlo[ii] = (unsigned)m; mhi[ii] = (unsigned)(m >> 32);
  }
  #pragma unroll
  for (int np = 0; np < 16; ++np) {
    uint4 z4 = *(const uint4*)&zk[rw * 68 + np * 4];
    const int p = np * 4, pb = p & 31;
    #pragma unroll
    for (int ii = 0; ii < 5; ++ii) {
      unsigned m = (p < 32) ? mlo[ii] : mhi[ii];
      unsigned s0 = sext1(m, pb),     s1 = sext1(m, pb + 1);
      unsigned s2 = sext1(m, pb + 2), s3 = sext1(m, pb + 3);
      unsigned a = uacc[ii];
      a = pkmax(a, z4.x & s0); a = pkmax(a, z4.y & s1);
      a = pkmax(a, z4.z & s2); a = pkmax(a, z4.w & s3);
      uacc[ii] = a;
    }
  }

  // ---- prune-read + atomic fold into one of 8 replicas.
  // Plain (possibly stale) read only suppresses provably-losing atomics;
  // correctness rests on the atomicMax itself.
  int* krep = keys + (blockIdx.x & (NREP - 1)) * KEYN;
  int cur0[5], cur1[5];
  #pragma unroll
  for (int ii = 0; ii < 5; ++ii) {
    int bc = bc0 + ii;
    if (bc < NBC) {
      cur0[ii] = krep[bc * 64 + 2 * rw];
      cur1[ii] = krep[bc * 64 + 2 * rw + 1];
    }
  }
  #pragma unroll
  for (int ii = 0; ii < 5; ++ii) {
    int bc = bc0 + ii;
    if (bc < NBC) {
      int lo = (int)(uacc[ii] & 0xFFFFu), hi = (int)(uacc[ii] >> 16);
      if (lo > cur0[ii]) atomicMax(&krep[bc * 64 + 2 * rw], lo);
      if (hi > cur1[ii]) atomicMax(&krep[bc * 64 + 2 * rw + 1], hi);
    }
  }
}

__global__ __launch_bounds__(256) void k2_fc(
    const int* __restrict__ keys,
    const float* __restrict__ b1, const float* __restrict__ w2,
    const float* __restrict__ b2, const float* __restrict__ w3,
    const float* __restrict__ b3,
    const float* __restrict__ fcw, const float* __restrict__ fcb,
    float* __restrict__ out)
{
  __shared__ float flat[4864];
  __shared__ float za[64], zb[64], zf[64];
  const int t = threadIdx.x;

  // zero_feat = fp32 MLP(0,0): tiny, recomputed per block
  if (t < 64) za[t] = lrelu(b1[t]);
  __syncthreads();
  if (t < 64) {
    float s = b2[t];
    #pragma unroll 8
    for (int k = 0; k < 64; ++k) s += w2[t * 64 + k] * za[k];
    zb[t] = lrelu(s);
  }
  __syncthreads();
  if (t < 64) {
    float s = b3[t];
    #pragma unroll 8
    for (int k = 0; k < 64; ++k) s += w3[t * 64 + k] * zb[k];
    zf[t] = lrelu(s);
  }
  __syncthreads();

  // fold 8 replicas with SIGNED max (untouched = poison/0 loses), decode
  for (int idx = t; idx < 4864; idx += 256) {
    int m = keys[idx];
    #pragma unroll
    for (int r = 1; r < NREP; ++r) m = max(m, keys[r * KEYN + idx]);
    unsigned um = (unsigned)m;
    float v;
    if (um - 1u < 0xFFFFu) {            // touched: valid key in [1, 0xFFFF]
      unsigned u = (um & 0x8000u) ? (um ^ 0x8000u) : (~um & 0xFFFFu);
      unsigned short us = (unsigned short)u;
      v = (float)__builtin_bit_cast(f16, us);
    } else {
      v = zf[idx & 63];                 // empty mask -> zero_feat
    }
    flat[idx] = v;
  }
  __syncthreads();

  const int wv = t >> 6, lane = t & 63;
  const int o = blockIdx.x * 4 + wv;          // 128 blocks x 4 waves = 512 outputs
  const float* wrow = fcw + o * 1216;
  float fa0 = 0.f, fa1 = 0.f, fa2 = 0.f, fa3 = 0.f;
  #pragma unroll
  for (int i = 0; i < 19; ++i) {
    int jj = i * 64 + lane;
    float wvv = wrow[jj];
    fa0 += wvv * flat[jj];
    fa1 += wvv * flat[1216 + jj];
    fa2 += wvv * flat[2432 + jj];
    fa3 += wvv * flat[3648 + jj];
  }
  #pragma unroll
  for (int off = 32; off > 0; off >>= 1) {
    fa0 += __shfl_xor(fa0, off);
    fa1 += __shfl_xor(fa1, off);
    fa2 += __shfl_xor(fa2, off);
    fa3 += __shfl_xor(fa3, off);
  }
  const float scale = 0.028676966733820225f;  // 1/sqrt(1216)
  float cb = fcb[o];
  if (lane < 18) {
    out[(0 * 18 + lane) * 512 + o] = fa0 * scale + cb;
    out[(1 * 18 + lane) * 512 + o] = fa1 * scale + cb;
    out[(2 * 18 + lane) * 512 + o] = fa2 * scale + cb;
    out[(3 * 18 + lane) * 512 + o] = fa3 * scale + cb;
  }
}

extern "C" void kernel_launch(void* const* d_in, const int* in_sizes, int n_in,
                              void* d_out, int out_size, void* d_ws, size_t ws_size,
                              hipStream_t stream)
{
  const int*   x    = (const int*)d_in[0];
  const float* grid = (const float*)d_in[1];
  const float* w1   = (const float*)d_in[2];
  const float* b1   = (const float*)d_in[3];
  const float* w2   = (const float*)d_in[4];
  const float* b2   = (const float*)d_in[5];
  const float* w3   = (const float*)d_in[6];
  const float* b3   = (const float*)d_in[7];
  const float* fcw  = (const float*)d_in[8];
  const float* fcb  = (const float*)d_in[9];
  float* out = (float*)d_out;

  int* keys = (int*)d_ws;   // 8 x 4864 i32 max-keys; NOT pre-zeroed (see kAB)

  hipLaunchKernelGGL(kAB, dim3(1024), dim3(512), 0, stream,
                     x, grid, w1, b1, w2, b2, w3, b3, keys);
  hipLaunchKernelGGL(k2_fc, dim3(128), dim3(256), 0, stream,
                     keys, b1, w2, b2, w3, b3, fcw, fcb, out);
}

// Round 12
// 119.210 us; speedup vs baseline: 1.3810x; 1.3810x over previous
//
#include <hip/hip_runtime.h>

#define NPTS  65536
#define NBC   76
#define NREP  8
#define KEYN  4864   // 76*64

typedef _Float16 f16;
typedef __fp16   h16x2 __attribute__((ext_vector_type(2)));   // cvt_pkrtz native type
typedef _Float16 f16x8 __attribute__((ext_vector_type(8)));
typedef float    f32x4 __attribute__((ext_vector_type(4)));

__device__ __forceinline__ float lrelu(float v) { return fmaxf(v, 0.01f * v); }

__device__ __forceinline__ unsigned pkrtz(float lo, float hi) {
  h16x2 p = __builtin_amdgcn_cvt_pkrtz(lo, hi);
  return __builtin_bit_cast(unsigned, p);
}
// packed f16 bits -> packed order-preserving u16 keys (larger key = larger float).
// Key 0 requires a NaN bit pattern => valid keys are in [1, 0xFFFF].
__device__ __forceinline__ unsigned pkey(unsigned u) {
  unsigned t = (u >> 15) & 0x00010001u;
  return u ^ (0x80008000u | (t * 0x7FFFu));
}
__device__ __forceinline__ unsigned pkmax(unsigned a, unsigned b) {
  unsigned d;
  asm("v_pk_max_u16 %0, %1, %2" : "=v"(d) : "v"(a), "v"(b));
  return d;
}
__device__ __forceinline__ unsigned sext1(unsigned x, int b) {
  return (unsigned)(((int)(x << (31 - b))) >> 31);
}
// 8 contiguous f32 -> f16x8 fragment (register-resident MFMA A-operand)
__device__ __forceinline__ f16x8 ldcvt8(const float* p) {
  float4 a = *(const float4*)p, b = *(const float4*)(p + 4);
  uint4 u = make_uint4(pkrtz(a.x, a.y), pkrtz(a.z, a.w),
                       pkrtz(b.x, b.y), pkrtz(b.z, b.w));
  return __builtin_bit_cast(f16x8, u);
}

// MFMA layer with register A-frags: acc = bias; 2 k-steps x 2 pt-tiles
__device__ __forceinline__ void mfma_layer_r(
    const f16x8* wr, const f16* __restrict__ B, const float* __restrict__ bias,
    int chq, int q, int pt0, int pt1, f32x4& acc0, f32x4& acc1)
{
  float4 bv = *(const float4*)(bias + chq);
  acc0 = (f32x4){bv.x, bv.y, bv.z, bv.w};
  acc1 = acc0;
  #pragma unroll
  for (int s = 0; s < 2; ++s) {
    int k0 = s * 32;
    f16x8 b0 = *(const f16x8*)&B[pt0 * 72 + k0 + q * 8];
    f16x8 b1 = *(const f16x8*)&B[pt1 * 72 + k0 + q * 8];
    acc0 = __builtin_amdgcn_mfma_f32_16x16x32_f16(wr[s], b0, acc0, 0, 0, 0);
    acc1 = __builtin_amdgcn_mfma_f32_16x16x32_f16(wr[s], b1, acc1, 0, 0, 0);
  }
}

// pointwise layer 1: wave wv -> channels wv*8..+7, pt = lane; writes zA[pt][k]
__device__ __forceinline__ void layer1(
    f16* __restrict__ zA, const float* __restrict__ w1,
    const float* __restrict__ b1, int wv, int lane, float g0, float g1)
{
  unsigned uo[4];
  #pragma unroll
  for (int p = 0; p < 4; ++p) {
    int j = wv * 8 + p * 2;
    float z0 = lrelu(w1[2 * j] * g0 + w1[2 * j + 1] * g1 + b1[j]);
    float z1 = lrelu(w1[2 * j + 2] * g0 + w1[2 * j + 3] * g1 + b1[j + 1]);
    uo[p] = pkrtz(z0, z1);
  }
  *(uint4*)&zA[lane * 72 + wv * 8] = make_uint4(uo[0], uo[1], uo[2], uo[3]);
}

// phase-B inner: masked max of one 64-pt tile into uacc[5]
__device__ __forceinline__ void phaseB(
    const unsigned* __restrict__ zk, const unsigned* mlo, const unsigned* mhi,
    unsigned* uacc, int rw)
{
  #pragma unroll
  for (int np = 0; np < 16; ++np) {
    uint4 z4 = *(const uint4*)&zk[rw * 68 + np * 4];
    const int p = np * 4, pb = p & 31;
    #pragma unroll
    for (int ii = 0; ii < 5; ++ii) {
      unsigned m = (p < 32) ? mlo[ii] : mhi[ii];
      unsigned s0 = sext1(m, pb),     s1 = sext1(m, pb + 1);
      unsigned s2 = sext1(m, pb + 2), s3 = sext1(m, pb + 3);
      unsigned a = uacc[ii];
      a = pkmax(a, z4.x & s0); a = pkmax(a, z4.y & s1);
      a = pkmax(a, z4.z & s2); a = pkmax(a, z4.w & s3);
      uacc[ii] = a;
    }
  }
}

// ------------- kAB: MLP (f16 MFMA) + masked max, fully fused, T=2 --------------
// __launch_bounds__(512,4): 128 VGPR/wave -> NO spills (the (512,8)=64-VGPR cap
// was forcing 32-VGPR allocation + scratch spill traffic, R10/R11 post-mortem).
// keys: NO pre-zeroing. Signed atomicMax: poison 0xAAAAAAAA is negative, valid
// keys are [1,0xFFFF] (positive) -> untouched slots lose every signed max; k2
// decodes (unsigned)(m-1) < 0xFFFF as "touched". Works for 0xAA or 0 init.
__global__ __launch_bounds__(512, 4) void kAB(
    const int* __restrict__ x, const float* __restrict__ grid,
    const float* __restrict__ w1, const float* __restrict__ b1,
    const float* __restrict__ w2, const float* __restrict__ b2,
    const float* __restrict__ w3, const float* __restrict__ b3,
    int* __restrict__ keys)
{
  // zA0/zA1/zB0/zB1 [64pt][72k] f16 (9216 B each); zk0/zk1 [32][68] u32 (8704 B)
  // alias zA0/zA1 (dead after layer2 reads, overwritten after barrier 2).
  __shared__ __align__(16) unsigned char smem[36864];
  __shared__ unsigned long long mb0[NBC], mb1[NBC];
  f16* zA0 = (f16*)(smem);
  f16* zA1 = (f16*)(smem + 9216);
  f16* zB0 = (f16*)(smem + 18432);
  f16* zB1 = (f16*)(smem + 27648);
  unsigned* zk0 = (unsigned*)(smem);          // alias zA0
  unsigned* zk1 = (unsigned*)(smem + 9216);   // alias zA1

  const int t = threadIdx.x, lane = t & 63, wv = t >> 6;
  const int n0 = blockIdx.x * 128;

  // ---- batch-0 x loads first: latency hides under weight cvt + layer1
  int xa[10];
  #pragma unroll
  for (int i = 0; i < 10; ++i) {
    int bc = wv + 8 * i;
    if (bc < NBC) xa[i] = x[(bc << 16) + n0 + lane];
  }

  float g0a = grid[n0 + lane],      g1a = grid[NPTS + n0 + lane];
  float g0b = grid[n0 + 64 + lane], g1b = grid[NPTS + n0 + 64 + lane];

  const int chb = (wv & 3) * 16, pth = (wv >> 2) * 32;
  const int c15 = lane & 15, q = lane >> 4;
  const int chq = chb + q * 4;
  const int pt0 = pth + c15, pt1 = pth + 16 + c15;
  const int r0 = chq >> 1;

  // weight A-fragments straight to registers
  f16x8 wr2[2], wr3[2];
  {
    const int row = (chb + c15) * 64 + q * 8;
    wr2[0] = ldcvt8(w2 + row);  wr2[1] = ldcvt8(w2 + row + 32);
    wr3[0] = ldcvt8(w3 + row);  wr3[1] = ldcvt8(w3 + row + 32);
  }

  layer1(zA0, w1, b1, wv, lane, g0a, g1a);
  layer1(zA1, w1, b1, wv, lane, g0b, g1b);

  // ballot tile 0 (xa long since arrived), then issue batch-1 x loads
  #pragma unroll
  for (int i = 0; i < 10; ++i) {
    int bc = wv + 8 * i;
    if (bc < NBC) {
      unsigned long long m = __ballot(xa[i] == 1);
      if (lane == 0) mb0[bc] = m;
    }
  }
  #pragma unroll
  for (int i = 0; i < 10; ++i) {
    int bc = wv + 8 * i;
    if (bc < NBC) xa[i] = x[(bc << 16) + n0 + 64 + lane];
  }
  __syncthreads();                      // barrier 1: zA0 + zA1 ready

  f32x4 a0, a1;
  mfma_layer_r(wr2, zA0, b2, chq, q, pt0, pt1, a0, a1);
  *(uint2*)&zB0[pt0 * 72 + chq] =
      make_uint2(pkrtz(lrelu(a0[0]), lrelu(a0[1])), pkrtz(lrelu(a0[2]), lrelu(a0[3])));
  *(uint2*)&zB0[pt1 * 72 + chq] =
      make_uint2(pkrtz(lrelu(a1[0]), lrelu(a1[1])), pkrtz(lrelu(a1[2]), lrelu(a1[3])));
  mfma_layer_r(wr2, zA1, b2, chq, q, pt0, pt1, a0, a1);
  *(uint2*)&zB1[pt0 * 72 + chq] =
      make_uint2(pkrtz(lrelu(a0[0]), lrelu(a0[1])), pkrtz(lrelu(a0[2]), lrelu(a0[3])));
  *(uint2*)&zB1[pt1 * 72 + chq] =
      make_uint2(pkrtz(lrelu(a1[0]), lrelu(a1[1])), pkrtz(lrelu(a1[2]), lrelu(a1[3])));
  __syncthreads();                      // barrier 2: zB0/zB1 ready, zA dead

  mfma_layer_r(wr3, zB0, b3, chq, q, pt0, pt1, a0, a1);
  zk0[r0 * 68 + pt0]       = pkey(pkrtz(lrelu(a0[0]), lrelu(a0[1])));
  zk0[(r0 + 1) * 68 + pt0] = pkey(pkrtz(lrelu(a0[2]), lrelu(a0[3])));
  zk0[r0 * 68 + pt1]       = pkey(pkrtz(lrelu(a1[0]), lrelu(a1[1])));
  zk0[(r0 + 1) * 68 + pt1] = pkey(pkrtz(lrelu(a1[2]), lrelu(a1[3])));
  mfma_layer_r(wr3, zB1, b3, chq, q, pt0, pt1, a0, a1);
  zk1[r0 * 68 + pt0]       = pkey(pkrtz(lrelu(a0[0]), lrelu(a0[1])));
  zk1[(r0 + 1) * 68 + pt0] = pkey(pkrtz(lrelu(a0[2]), lrelu(a0[3])));
  zk1[r0 * 68 + pt1]       = pkey(pkrtz(lrelu(a1[0]), lrelu(a1[1])));
  zk1[(r0 + 1) * 68 + pt1] = pkey(pkrtz(lrelu(a1[2]), lrelu(a1[3])));

  // ballot tile 1
  #pragma unroll
  for (int i = 0; i < 10; ++i) {
    int bc = wv + 8 * i;
    if (bc < NBC) {
      unsigned long long m = __ballot(xa[i] == 1);
      if (lane == 0) mb1[bc] = m;
    }
  }
  __syncthreads();                      // barrier 3: zk0/zk1 + masks ready

  // ---- phase B: thread -> row rw (ch pair) x 5 bc
  const int rw = t & 31, bg = t >> 5;
  const int bc0 = bg * 5;

  unsigned uacc[5] = {0u, 0u, 0u, 0u, 0u};
  unsigned mlo[5], mhi[5];
  #pragma unroll
  for (int ii = 0; ii < 5; ++ii) {
    int bc = bc0 + ii;
    unsigned long long m = (bc < NBC) ? mb0[bc] : 0ull;
    mlo[ii] = (unsigned)m; mhi[ii] = (unsigned)(m >> 32);
  }
  phaseB(zk0, mlo, mhi, uacc, rw);
  #pragma unroll
  for (int ii = 0; ii < 5; ++ii) {
    int bc = bc0 + ii;
    unsigned long long m = (bc < NBC) ? mb1[bc] : 0ull;
    mlo[ii] = (unsigned)m; mhi[ii] = (unsigned)(m >> 32);
  }
  phaseB(zk1, mlo, mhi, uacc, rw);

  int* krep = keys + (blockIdx.x & (NREP - 1)) * KEYN;
  #pragma unroll
  for (int ii = 0; ii < 5; ++ii) {
    int bc = bc0 + ii;
    if (bc < NBC) {
      int lo = (int)(uacc[ii] & 0xFFFFu), hi = (int)(uacc[ii] >> 16);
      if (lo) atomicMax(&krep[bc * 64 + 2 * rw], lo);
      if (hi) atomicMax(&krep[bc * 64 + 2 * rw + 1], hi);
    }
  }
}

__global__ __launch_bounds__(256) void k2_fc(
    const int* __restrict__ keys,
    const float* __restrict__ b1, const float* __restrict__ w2,
    const float* __restrict__ b2, const float* __restrict__ w3,
    const float* __restrict__ b3,
    const float* __restrict__ fcw, const float* __restrict__ fcb,
    float* __restrict__ out)
{
  __shared__ float flat[4864];
  __shared__ float za[64], zb[64], zf[64];
  const int t = threadIdx.x;

  // zero_feat = fp32 MLP(0,0): tiny, recomputed per block
  if (t < 64) za[t] = lrelu(b1[t]);
  __syncthreads();
  if (t < 64) {
    float s = b2[t];
    #pragma unroll 8
    for (int k = 0; k < 64; ++k) s += w2[t * 64 + k] * za[k];
    zb[t] = lrelu(s);
  }
  __syncthreads();
  if (t < 64) {
    float s = b3[t];
    #pragma unroll 8
    for (int k = 0; k < 64; ++k) s += w3[t * 64 + k] * zb[k];
    zf[t] = lrelu(s);
  }
  __syncthreads();

  // fold 8 replicas with SIGNED max (untouched = poison/0 loses), decode
  for (int idx = t; idx < 4864; idx += 256) {
    int m = keys[idx];
    #pragma unroll
    for (int r = 1; r < NREP; ++r) m = max(m, keys[r * KEYN + idx]);
    unsigned um = (unsigned)m;
    float v;
    if (um - 1u < 0xFFFFu) {            // touched: valid key in [1, 0xFFFF]
      unsigned u = (um & 0x8000u) ? (um ^ 0x8000u) : (~um & 0xFFFFu);
      unsigned short us = (unsigned short)u;
      v = (float)__builtin_bit_cast(f16, us);
    } else {
      v = zf[idx & 63];                 // empty mask -> zero_feat
    }
    flat[idx] = v;
  }
  __syncthreads();

  const int wv = t >> 6, lane = t & 63;
  const int o = blockIdx.x * 4 + wv;          // 128 blocks x 4 waves = 512 outputs
  const float* wrow = fcw + o * 1216;
  float fa0 = 0.f, fa1 = 0.f, fa2 = 0.f, fa3 = 0.f;
  #pragma unroll
  for (int i = 0; i < 19; ++i) {
    int jj = i * 64 + lane;
    float wvv = wrow[jj];
    fa0 += wvv * flat[jj];
    fa1 += wvv * flat[1216 + jj];
    fa2 += wvv * flat[2432 + jj];
    fa3 += wvv * flat[3648 + jj];
  }
  #pragma unroll
  for (int off = 32; off > 0; off >>= 1) {
    fa0 += __shfl_xor(fa0, off);
    fa1 += __shfl_xor(fa1, off);
    fa2 += __shfl_xor(fa2, off);
    fa3 += __shfl_xor(fa3, off);
  }
  const float scale = 0.028676966733820225f;  // 1/sqrt(1216)
  float cb = fcb[o];
  if (lane < 18) {
    out[(0 * 18 + lane) * 512 + o] = fa0 * scale + cb;
    out[(1 * 18 + lane) * 512 + o] = fa1 * scale + cb;
    out[(2 * 18 + lane) * 512 + o] = fa2 * scale + cb;
    out[(3 * 18 + lane) * 512 + o] = fa3 * scale + cb;
  }
}

extern "C" void kernel_launch(void* const* d_in, const int* in_sizes, int n_in,
                              void* d_out, int out_size, void* d_ws, size_t ws_size,
                              hipStream_t stream)
{
  const int*   x    = (const int*)d_in[0];
  const float* grid = (const float*)d_in[1];
  const float* w1   = (const float*)d_in[2];
  const float* b1   = (const float*)d_in[3];
  const float* w2   = (const float*)d_in[4];
  const float* b2   = (const float*)d_in[5];
  const float* w3   = (const float*)d_in[6];
  const float* b3   = (const float*)d_in[7];
  const float* fcw  = (const float*)d_in[8];
  const float* fcb  = (const float*)d_in[9];
  float* out = (float*)d_out;

  int* keys = (int*)d_ws;   // 8 x 4864 i32 max-keys; NOT pre-zeroed (see kAB)

  hipLaunchKernelGGL(kAB, dim3(512), dim3(512), 0, stream,
                     x, grid, w1, b1, w2, b2, w3, b3, keys);
  hipLaunchKernelGGL(k2_fc, dim3(128), dim3(256), 0, stream,
                     keys, b1, w2, b2, w3, b3, fcw, fcb, out);
}